// Round 1
// baseline (1998.440 us; speedup 1.0000x reference)
//
#include <hip/hip_runtime.h>
#include <hip/hip_bf16.h>

#define B_  4096
#define T_  255
#define V_  32000
#define E_  64
#define H_  64
#define D1_ 32

// ---------------------------------------------------------------------------
// Kernel 1: fused embedding-gather + LSTM over T=255 steps.
// 256 blocks (1 per CU, LDS-capped), 256 threads = 4 waves, 4 rows per wave.
// Lane j owns hidden unit j. Weights live in LDS gate-interleaved as float4:
//   wq[k][j] = { W[k][j], W[k][64+j], W[k][128+j], W[k][192+j] }  (i,f,g,o)
// so each lane issues one ds_read_b128 per k per matrix. x_k / h_k broadcasts
// come from v_readlane (SGPR operand into v_fma) — no LDS traffic for them.
// ---------------------------------------------------------------------------
__global__ __launch_bounds__(256, 1)
void lstm_kernel(const int* __restrict__ idx,
                 const float* __restrict__ emb,
                 const float* __restrict__ Wx,
                 const float* __restrict__ Wh,
                 const float* __restrict__ b,
                 float* __restrict__ h_out)
{
    __shared__ float4 wqx[64][64];   // 64 KiB
    __shared__ float4 wqh[64][64];   // 64 KiB
    __shared__ float4 bq[64];        // 1 KiB

    const int tid = threadIdx.x;

    // ---- stage + reorder weights (once) ----
    #pragma unroll
    for (int i = 0; i < 16; ++i) {
        int flat = i * 256 + tid;          // 0..4095
        int k = flat >> 6, j = flat & 63;
        const float* wr = Wx + k * 256;
        wqx[k][j] = make_float4(wr[j], wr[64 + j], wr[128 + j], wr[192 + j]);
        const float* hr = Wh + k * 256;
        wqh[k][j] = make_float4(hr[j], hr[64 + j], hr[128 + j], hr[192 + j]);
    }
    if (tid < 64) bq[tid] = make_float4(b[tid], b[64 + tid], b[128 + tid], b[192 + tid]);
    __syncthreads();

    const int lane = tid & 63;
    const int wave = tid >> 6;
    const int r0   = blockIdx.x * 16 + wave * 4;   // 4 rows per wave

    float h[4] = {0.f, 0.f, 0.f, 0.f};
    float c[4] = {0.f, 0.f, 0.f, 0.f};
    float xa[4], xb[4];

    auto load_x = [&](int t, float* xv) {
        int iv = 0;
        if (lane < 4) iv = idx[(r0 + lane) * T_ + t];
        #pragma unroll
        for (int r = 0; r < 4; ++r) {
            int row = __builtin_amdgcn_readlane(iv, r);      // uniform
            xv[r] = emb[row * E_ + lane];                    // coalesced 256B
        }
    };

    auto step = [&](const float* xv) {
        float4 bias = bq[lane];
        float4 acc[4];
        #pragma unroll
        for (int r = 0; r < 4; ++r) acc[r] = bias;

        #pragma unroll 8
        for (int k = 0; k < 64; ++k) {
            float4 wx = wqx[k][lane];
            float4 wh = wqh[k][lane];
            #pragma unroll
            for (int r = 0; r < 4; ++r) {
                float xs = __uint_as_float(__builtin_amdgcn_readlane(__float_as_uint(xv[r]), k));
                float hs = __uint_as_float(__builtin_amdgcn_readlane(__float_as_uint(h[r]),  k));
                acc[r].x = fmaf(wx.x, xs, acc[r].x);
                acc[r].y = fmaf(wx.y, xs, acc[r].y);
                acc[r].z = fmaf(wx.z, xs, acc[r].z);
                acc[r].w = fmaf(wx.w, xs, acc[r].w);
                acc[r].x = fmaf(wh.x, hs, acc[r].x);
                acc[r].y = fmaf(wh.y, hs, acc[r].y);
                acc[r].z = fmaf(wh.z, hs, acc[r].z);
                acc[r].w = fmaf(wh.w, hs, acc[r].w);
            }
        }
        #pragma unroll
        for (int r = 0; r < 4; ++r) {
            float ig = 1.f / (1.f + __expf(-acc[r].x));
            float fg = 1.f / (1.f + __expf(-acc[r].y));
            float gg = tanhf(acc[r].z);
            float og = 1.f / (1.f + __expf(-acc[r].w));
            c[r] = fg * c[r] + ig * gg;
            h[r] = og * tanhf(c[r]);
        }
    };

    load_x(0, xa);
    for (int t = 0; t < T_; t += 2) {
        if (t + 1 < T_) load_x(t + 1, xb);   // prefetch while computing t
        step(xa);
        if (t + 2 < T_) load_x(t + 2, xa);
        if (t + 1 < T_) step(xb);
    }

    #pragma unroll
    for (int r = 0; r < 4; ++r)
        h_out[(r0 + r) * H_ + lane] = h[r];
}

// ---------------------------------------------------------------------------
// Kernel 2: out32 = relu(h @ W1 + b1)   [4096,64]@[64,32] — tiny
// ---------------------------------------------------------------------------
__global__ __launch_bounds__(256)
void head1_kernel(const float* __restrict__ h,
                  const float* __restrict__ W1,
                  const float* __restrict__ b1,
                  float* __restrict__ out32)
{
    int i = blockIdx.x * 256 + threadIdx.x;   // over 4096*32
    int r = i >> 5, d = i & 31;
    float a = b1[d];
    #pragma unroll
    for (int k = 0; k < 64; ++k)
        a = fmaf(h[r * H_ + k], W1[k * D1_ + d], a);
    out32[i] = fmaxf(a, 0.f);
}

// ---------------------------------------------------------------------------
// Kernel 3: logits = out32 @ W2 + b2, softmax over V=32000.
// Two recompute passes (logits never round-trip to HBM):
//   PASS 1: per-row sum of exp(logit) -> deterministic partials [B][16]
//   PASS 2: out = exp(logit) / sum
// Logits are bounded (|l| <~ 6), so exp without max-subtraction is safe.
// Grid (16 vtiles of 2048 cols, 256 row-tiles of 16 rows). Each thread owns
// 8 columns; per k one coalesced W2 load feeds 16 row-FMAs x 8 cols.
// ---------------------------------------------------------------------------
template <int PASS>
__global__ __launch_bounds__(256)
void head2_kernel(const float* __restrict__ out32,
                  const float* __restrict__ W2,
                  const float* __restrict__ b2,
                  float* __restrict__ partial,   // [B][16]
                  float* __restrict__ out)
{
    __shared__ float A[32][16];      // A[k][r]
    __shared__ float wsum[4][16];
    __shared__ float sinv[16];

    const int tid = threadIdx.x;
    const int vt  = blockIdx.x;          // 0..15
    const int r0  = blockIdx.y * 16;     // row tile base

    for (int i = tid; i < 512; i += 256) {
        int r = i >> 5, k = i & 31;
        A[k][r] = out32[(r0 + r) * D1_ + k];
    }
    if (PASS == 2 && tid < 16) {
        float s = 0.f;
        #pragma unroll
        for (int v = 0; v < 16; ++v) s += partial[(r0 + tid) * 16 + v];
        sinv[tid] = 1.f / s;
    }
    __syncthreads();

    const int cbeg = vt * 2048;
    float acc[8][16];
    #pragma unroll
    for (int cc = 0; cc < 8; ++cc)
        #pragma unroll
        for (int r = 0; r < 16; ++r) acc[cc][r] = 0.f;

    #pragma unroll 4
    for (int k = 0; k < 32; ++k) {
        float ar[16];
        #pragma unroll
        for (int r = 0; r < 16; ++r) ar[r] = A[k][r];
        #pragma unroll
        for (int cc = 0; cc < 8; ++cc) {
            int cidx = cbeg + tid + cc * 256;
            float w = (cidx < V_) ? W2[k * V_ + cidx] : 0.f;
            #pragma unroll
            for (int r = 0; r < 16; ++r) acc[cc][r] = fmaf(ar[r], w, acc[cc][r]);
        }
    }

    float sumloc[16];
    #pragma unroll
    for (int r = 0; r < 16; ++r) sumloc[r] = 0.f;

    #pragma unroll
    for (int cc = 0; cc < 8; ++cc) {
        int cidx = cbeg + tid + cc * 256;
        if (cidx < V_) {
            float bb = b2[cidx];
            #pragma unroll
            for (int r = 0; r < 16; ++r) {
                float e = __expf(acc[cc][r] + bb);
                if (PASS == 1) sumloc[r] += e;
                else           out[(r0 + r) * V_ + cidx] = e * sinv[r];
            }
        }
    }

    if (PASS == 1) {
        #pragma unroll
        for (int r = 0; r < 16; ++r) {
            float v = sumloc[r];
            #pragma unroll
            for (int off = 32; off; off >>= 1) v += __shfl_xor(v, off, 64);
            if ((tid & 63) == 0) wsum[tid >> 6][r] = v;
        }
        __syncthreads();
        if (tid < 16)
            partial[(r0 + tid) * 16 + vt] =
                wsum[0][tid] + wsum[1][tid] + wsum[2][tid] + wsum[3][tid];
    }
}

// ---------------------------------------------------------------------------
extern "C" void kernel_launch(void* const* d_in, const int* in_sizes, int n_in,
                              void* d_out, int out_size, void* d_ws, size_t ws_size,
                              hipStream_t stream)
{
    (void)in_sizes; (void)n_in; (void)out_size; (void)ws_size;

    const int*   idx = (const int*)  d_in[0];
    const float* emb = (const float*)d_in[1];
    const float* Wx  = (const float*)d_in[2];
    const float* Wh  = (const float*)d_in[3];
    const float* bl  = (const float*)d_in[4];
    const float* W1  = (const float*)d_in[5];
    const float* b1  = (const float*)d_in[6];
    const float* W2  = (const float*)d_in[7];
    const float* b2  = (const float*)d_in[8];
    float* out = (float*)d_out;

    float* h     = (float*)d_ws;               // 4096*64 f32
    float* out32 = h + B_ * H_;                // 4096*32 f32
    float* part  = out32 + B_ * D1_;           // 4096*16 f32

    lstm_kernel<<<256, 256, 0, stream>>>(idx, emb, Wx, Wh, bl, h);
    head1_kernel<<<(B_ * D1_) / 256, 256, 0, stream>>>(h, W1, b1, out32);

    dim3 g3(16, B_ / 16);
    head2_kernel<1><<<g3, 256, 0, stream>>>(out32, W2, b2, part, out);
    head2_kernel<2><<<g3, 256, 0, stream>>>(out32, W2, b2, part, out);
}

// Round 2
// 1682.359 us; speedup vs baseline: 1.1879x; 1.1879x over previous
//
#include <hip/hip_runtime.h>
#include <hip/hip_bf16.h>

#define B_  4096
#define T_  255
#define V_  32000
#define E_  64
#define H_  64
#define D1_ 32

__device__ __forceinline__ float fast_sigmoid(float x) {
    // 1/(1+e^-x) with v_rcp_f32 (~1 ulp) instead of IEEE div
    return __builtin_amdgcn_rcpf(1.f + __expf(-x));
}
__device__ __forceinline__ float fast_tanh(float x) {
    // tanh(x) = 1 - 2/(e^{2x}+1); large |x| degrades gracefully to +/-1
    return 1.f - 2.f * __builtin_amdgcn_rcpf(1.f + __expf(2.f * x));
}
__device__ __forceinline__ float bcast(float v, int k) {
    return __uint_as_float(__builtin_amdgcn_readlane(__float_as_uint(v), k));
}

// ---------------------------------------------------------------------------
// Kernel 1: fused embedding-gather + LSTM over T=255 steps.
// 256 blocks (1/CU), 512 threads = 8 waves (2/SIMD for latency hiding),
// 2 rows per wave. Lane j owns hidden unit j, gates i,f,g,o packed in float4.
// ---------------------------------------------------------------------------
__global__ __launch_bounds__(512, 2)
void lstm_kernel(const int* __restrict__ idx,
                 const float* __restrict__ emb,
                 const float* __restrict__ Wx,
                 const float* __restrict__ Wh,
                 const float* __restrict__ b,
                 float* __restrict__ h_out)
{
    __shared__ float4 wqx[64][64];   // 64 KiB
    __shared__ float4 wqh[64][64];   // 64 KiB
    __shared__ float4 bq[64];        // 1 KiB

    const int tid = threadIdx.x;

    #pragma unroll
    for (int i = 0; i < 8; ++i) {
        int flat = i * 512 + tid;          // 0..4095
        int k = flat >> 6, j = flat & 63;
        const float* wr = Wx + k * 256;
        wqx[k][j] = make_float4(wr[j], wr[64 + j], wr[128 + j], wr[192 + j]);
        const float* hr = Wh + k * 256;
        wqh[k][j] = make_float4(hr[j], hr[64 + j], hr[128 + j], hr[192 + j]);
    }
    if (tid < 64) bq[tid] = make_float4(b[tid], b[64 + tid], b[128 + tid], b[192 + tid]);
    __syncthreads();

    const int lane = tid & 63;
    const int wave = tid >> 6;                    // 0..7
    const int r0   = blockIdx.x * 16 + wave * 2;  // 2 rows per wave

    float h0 = 0.f, h1 = 0.f, c0 = 0.f, c1 = 0.f;
    float2 xa, xb;

    auto load_x = [&](int t, float2& xv) {
        int iv = 0;
        if (lane < 2) iv = idx[(r0 + lane) * T_ + t];
        int ra = __builtin_amdgcn_readlane(iv, 0);
        int rb = __builtin_amdgcn_readlane(iv, 1);
        xv.x = emb[ra * E_ + lane];               // coalesced 256B
        xv.y = emb[rb * E_ + lane];
    };

    auto step = [&](float2 xv) {
        float4 a0 = bq[lane];
        float4 a1 = a0;

        #pragma unroll 16
        for (int k = 0; k < 64; ++k) {
            float4 wx = wqx[k][lane];
            float4 wh = wqh[k][lane];
            float xs0 = bcast(xv.x, k), xs1 = bcast(xv.y, k);
            float hs0 = bcast(h0,   k), hs1 = bcast(h1,   k);
            a0.x = fmaf(wx.x, xs0, a0.x);  a0.y = fmaf(wx.y, xs0, a0.y);
            a0.z = fmaf(wx.z, xs0, a0.z);  a0.w = fmaf(wx.w, xs0, a0.w);
            a0.x = fmaf(wh.x, hs0, a0.x);  a0.y = fmaf(wh.y, hs0, a0.y);
            a0.z = fmaf(wh.z, hs0, a0.z);  a0.w = fmaf(wh.w, hs0, a0.w);
            a1.x = fmaf(wx.x, xs1, a1.x);  a1.y = fmaf(wx.y, xs1, a1.y);
            a1.z = fmaf(wx.z, xs1, a1.z);  a1.w = fmaf(wx.w, xs1, a1.w);
            a1.x = fmaf(wh.x, hs1, a1.x);  a1.y = fmaf(wh.y, hs1, a1.y);
            a1.z = fmaf(wh.z, hs1, a1.z);  a1.w = fmaf(wh.w, hs1, a1.w);
        }
        c0 = fast_sigmoid(a0.y) * c0 + fast_sigmoid(a0.x) * fast_tanh(a0.z);
        h0 = fast_sigmoid(a0.w) * fast_tanh(c0);
        c1 = fast_sigmoid(a1.y) * c1 + fast_sigmoid(a1.x) * fast_tanh(a1.z);
        h1 = fast_sigmoid(a1.w) * fast_tanh(c1);
    };

    load_x(0, xa);
    for (int t = 0; t < T_; t += 2) {
        if (t + 1 < T_) load_x(t + 1, xb);   // prefetch while computing t
        step(xa);
        if (t + 2 < T_) load_x(t + 2, xa);
        if (t + 1 < T_) step(xb);
    }

    h_out[r0 * H_ + lane]       = h0;
    h_out[(r0 + 1) * H_ + lane] = h1;
}

// ---------------------------------------------------------------------------
// Kernel 2: out32 = relu(h @ W1 + b1)   [4096,64]@[64,32] — tiny
// ---------------------------------------------------------------------------
__global__ __launch_bounds__(256)
void head1_kernel(const float* __restrict__ h,
                  const float* __restrict__ W1,
                  const float* __restrict__ b1,
                  float* __restrict__ out32)
{
    int i = blockIdx.x * 256 + threadIdx.x;   // over 4096*32
    int r = i >> 5, d = i & 31;
    float a = b1[d];
    #pragma unroll
    for (int k = 0; k < 64; ++k)
        a = fmaf(h[r * H_ + k], W1[k * D1_ + d], a);
    out32[i] = fmaxf(a, 0.f);
}

// ---------------------------------------------------------------------------
// Kernel 3: logits = out32 @ W2 + b2, softmax over V=32000, 2 recompute
// passes (no logit round-trip). 32 rows/block, 4 cols/thread: W2 traffic
// halved vs 16-row version. Grid = (rowgroup, vtile) so consecutive blocks
// share a W2 vtile slice (XCD L2 locality; W2 = 4 MB = one XCD's L2).
// ---------------------------------------------------------------------------
template <int PASS>
__global__ __launch_bounds__(256, 2)
void head2_kernel(const float* __restrict__ out32,
                  const float* __restrict__ W2,
                  const float* __restrict__ b2,
                  float* __restrict__ partial,   // [B][32]
                  float* __restrict__ out)
{
    __shared__ float A[32][32];      // A[k][r]
    __shared__ float wsum[4][32];
    __shared__ float sinv[32];

    const int tid = threadIdx.x;
    const int vt  = blockIdx.y;          // 0..31
    const int r0  = blockIdx.x * 32;     // row tile base

    for (int i = tid; i < 1024; i += 256) {
        int r = i >> 5, k = i & 31;
        A[k][r] = out32[(r0 + r) * D1_ + k];
    }
    if (PASS == 2 && tid < 32) {
        float s = 0.f;
        #pragma unroll
        for (int v = 0; v < 32; ++v) s += partial[(r0 + tid) * 32 + v];
        sinv[tid] = 1.f / s;
    }
    __syncthreads();

    const int cbeg = vt * 1024;
    float acc[4][32];
    #pragma unroll
    for (int cc = 0; cc < 4; ++cc)
        #pragma unroll
        for (int r = 0; r < 32; ++r) acc[cc][r] = 0.f;

    #pragma unroll 2
    for (int k = 0; k < 32; ++k) {
        float ar[32];
        #pragma unroll
        for (int r = 0; r < 32; ++r) ar[r] = A[k][r];
        #pragma unroll
        for (int cc = 0; cc < 4; ++cc) {
            int cidx = cbeg + tid + cc * 256;
            float w = (cidx < V_) ? W2[k * V_ + cidx] : 0.f;
            #pragma unroll
            for (int r = 0; r < 32; ++r) acc[cc][r] = fmaf(ar[r], w, acc[cc][r]);
        }
    }

    float sumloc[32];
    #pragma unroll
    for (int r = 0; r < 32; ++r) sumloc[r] = 0.f;

    #pragma unroll
    for (int cc = 0; cc < 4; ++cc) {
        int cidx = cbeg + tid + cc * 256;
        if (cidx < V_) {
            float bb = b2[cidx];
            #pragma unroll
            for (int r = 0; r < 32; ++r) {
                float e = __expf(acc[cc][r] + bb);
                if (PASS == 1) sumloc[r] += e;
                else           out[(r0 + r) * V_ + cidx] = e * sinv[r];
            }
        }
    }

    if (PASS == 1) {
        #pragma unroll
        for (int r = 0; r < 32; ++r) {
            float v = sumloc[r];
            #pragma unroll
            for (int off = 32; off; off >>= 1) v += __shfl_xor(v, off, 64);
            if ((tid & 63) == 0) wsum[tid >> 6][r] = v;
        }
        __syncthreads();
        if (tid < 32)
            partial[(r0 + tid) * 32 + vt] =
                wsum[0][tid] + wsum[1][tid] + wsum[2][tid] + wsum[3][tid];
    }
}

// ---------------------------------------------------------------------------
extern "C" void kernel_launch(void* const* d_in, const int* in_sizes, int n_in,
                              void* d_out, int out_size, void* d_ws, size_t ws_size,
                              hipStream_t stream)
{
    (void)in_sizes; (void)n_in; (void)out_size; (void)ws_size;

    const int*   idx = (const int*)  d_in[0];
    const float* emb = (const float*)d_in[1];
    const float* Wx  = (const float*)d_in[2];
    const float* Wh  = (const float*)d_in[3];
    const float* bl  = (const float*)d_in[4];
    const float* W1  = (const float*)d_in[5];
    const float* b1  = (const float*)d_in[6];
    const float* W2  = (const float*)d_in[7];
    const float* b2  = (const float*)d_in[8];
    float* out = (float*)d_out;

    float* h     = (float*)d_ws;               // 4096*64 f32
    float* out32 = h + B_ * H_;                // 4096*32 f32
    float* part  = out32 + B_ * D1_;           // 4096*32 f32

    lstm_kernel<<<256, 512, 0, stream>>>(idx, emb, Wx, Wh, bl, h);
    head1_kernel<<<(B_ * D1_) / 256, 256, 0, stream>>>(h, W1, b1, out32);

    dim3 g3(B_ / 32, 32);
    head2_kernel<1><<<g3, 256, 0, stream>>>(out32, W2, b2, part, out);
    head2_kernel<2><<<g3, 256, 0, stream>>>(out32, W2, b2, part, out);
}

// Round 3
// 598.957 us; speedup vs baseline: 3.3365x; 2.8088x over previous
//
#include <hip/hip_runtime.h>
#include <hip/hip_bf16.h>

#define B_  4096
#define T_  255
#define V_  32000
#define E_  64
#define H_  64
#define D1_ 32

typedef __attribute__((ext_vector_type(8))) short bf16x8;   // 8 bf16 = 4 VGPR
typedef __attribute__((ext_vector_type(4))) float f32x4;

__device__ __forceinline__ ushort f2bf(float f) {
    __hip_bfloat16 h = __float2bfloat16(f);   // RNE
    return *reinterpret_cast<ushort*>(&h);
}
__device__ __forceinline__ float fast_sigmoid(float x) {
    return __builtin_amdgcn_rcpf(1.f + __expf(-x));
}
__device__ __forceinline__ float fast_tanh(float x) {
    return 1.f - 2.f * __builtin_amdgcn_rcpf(1.f + __expf(2.f * x));
}

// Swizzled byte offset inside a [16 rows][128 bf16] (256 B/row) A-tile.
// XOR of row bits into the 16B-slot bits: A-frag column reads (16 rows,
// same 16B slot) would otherwise be a 16-way bank conflict.
__device__ __forceinline__ int a_off(int row, int colb) {
    return row * 256 + (colb ^ ((row & 7) << 4));
}

// ---------------------------------------------------------------------------
// Fused embedding-gather + LSTM, bf16 MFMA.
// Block = 16 batch rows, 4 waves. Wave w owns hidden units j in [16w,16w+16),
// computing gate tiles (i,f,g,o) as 4 N-tiles x 4 K-slices of 16x16x32 MFMA.
// Weights persist in VGPRs as B-frags. A = [x(t) | h(t-1)] bf16 in LDS,
// double-buffered, XOR-swizzled. c/h state lives in the C-frag layout
// (col=lane&15, row=(lane>>4)*4+reg), so gate math is per-lane VALU only.
// ---------------------------------------------------------------------------
__global__ __launch_bounds__(256, 1)
void lstm_mfma_kernel(const int* __restrict__ idx,
                      const float* __restrict__ emb,
                      const float* __restrict__ Wx,
                      const float* __restrict__ Wh,
                      const float* __restrict__ b,
                      float* __restrict__ h_out)
{
    __shared__ __align__(16) char abuf[2][4096];   // [buf][16 rows][128 bf16]

    const int tid  = threadIdx.x;
    const int lane = tid & 63;
    const int wave = tid >> 6;          // 0..3
    const int r0   = blockIdx.x * 16;

    const int lrow = lane & 15;         // A-row / D-col index
    const int lhi  = lane >> 4;         // 0..3

    // ---- persistent B fragments: lane holds W[s*32 + lhi*8 + i][g*64 + 16w + lrow]
    bf16x8 bw[16];                      // [g*4 + s]
    const int jcol = wave * 16 + lrow;  // this lane's hidden unit j
    #pragma unroll
    for (int g = 0; g < 4; ++g) {
        const int col = g * 64 + jcol;
        #pragma unroll
        for (int s = 0; s < 4; ++s) {
            bf16x8 f;
            #pragma unroll
            for (int i = 0; i < 8; ++i) {
                int k = s * 32 + lhi * 8 + i;
                float v = (k < 64) ? Wx[k * 256 + col] : Wh[(k - 64) * 256 + col];
                f[i] = (short)f2bf(v);
            }
            bw[g * 4 + s] = f;
        }
    }
    float bias[4];
    #pragma unroll
    for (int g = 0; g < 4; ++g) bias[g] = b[g * 64 + jcol];

    // ---- prologue: buf0 = [x(0) | h(-1)=0] ----
    const int xrow = tid >> 4, xc = tid & 15;   // thread -> (row, 4-col chunk)
    {
        *(ushort4*)(&abuf[0][a_off(xrow, 128 + xc * 8)]) = make_ushort4(0, 0, 0, 0);
        int iv = idx[(r0 + xrow) * T_ + 0];
        float4 xv = ((const float4*)(emb + iv * E_))[xc];
        *(ushort4*)(&abuf[0][a_off(xrow, xc * 8)]) =
            make_ushort4(f2bf(xv.x), f2bf(xv.y), f2bf(xv.z), f2bf(xv.w));
    }
    __syncthreads();

    float cst[4]  = {0.f, 0.f, 0.f, 0.f};
    float hreg[4] = {0.f, 0.f, 0.f, 0.f};

    for (int t = 0; t < T_; ++t) {
        const int p = t & 1;

        // prefetch x(t+1) into regs (HBM latency hides under MFMA+VALU)
        float4 xv;
        const bool havex = (t + 1 < T_);
        if (havex) {
            int iv = idx[(r0 + xrow) * T_ + (t + 1)];
            xv = ((const float4*)(emb + iv * E_))[xc];
        }

        // z = bias + A @ W   (A = [x|h], 16x128 ; W = 128x256)
        f32x4 z[4];
        #pragma unroll
        for (int g = 0; g < 4; ++g) z[g] = (f32x4){bias[g], bias[g], bias[g], bias[g]};
        #pragma unroll
        for (int s = 0; s < 4; ++s) {
            bf16x8 af = *(const bf16x8*)(&abuf[p][a_off(lrow, s * 64 + lhi * 16)]);
            #pragma unroll
            for (int g = 0; g < 4; ++g)
                z[g] = __builtin_amdgcn_mfma_f32_16x16x32_bf16(af, bw[g * 4 + s], z[g], 0, 0, 0);
        }

        // gates -> c,h ; write h(t) bf16 into buf[p^1] h-region
        #pragma unroll
        for (int r = 0; r < 4; ++r) {
            float zi = z[0][r], zf = z[1][r], zg = z[2][r], zo = z[3][r];
            float cn = fast_sigmoid(zf) * cst[r] + fast_sigmoid(zi) * fast_tanh(zg);
            cst[r] = cn;
            float hn = fast_sigmoid(zo) * fast_tanh(cn);
            hreg[r] = hn;
            *(ushort*)(&abuf[p ^ 1][a_off(lhi * 4 + r, 128 + 2 * jcol)]) = f2bf(hn);
        }

        // write x(t+1) into buf[p^1] x-region
        if (havex)
            *(ushort4*)(&abuf[p ^ 1][a_off(xrow, xc * 8)]) =
                make_ushort4(f2bf(xv.x), f2bf(xv.y), f2bf(xv.z), f2bf(xv.w));

        __syncthreads();   // one barrier/step (double buffer)
    }

    #pragma unroll
    for (int r = 0; r < 4; ++r)
        h_out[(r0 + lhi * 4 + r) * H_ + jcol] = hreg[r];
}

// ---------------------------------------------------------------------------
// Kernel 2: out32 = relu(h @ W1 + b1)   [4096,64]@[64,32] — tiny
// ---------------------------------------------------------------------------
__global__ __launch_bounds__(256)
void head1_kernel(const float* __restrict__ h,
                  const float* __restrict__ W1,
                  const float* __restrict__ b1,
                  float* __restrict__ out32)
{
    int i = blockIdx.x * 256 + threadIdx.x;   // over 4096*32
    int r = i >> 5, d = i & 31;
    float a = b1[d];
    #pragma unroll
    for (int k = 0; k < 64; ++k)
        a = fmaf(h[r * H_ + k], W1[k * D1_ + d], a);
    out32[i] = fmaxf(a, 0.f);
}

// ---------------------------------------------------------------------------
// Kernel 3: logits = out32 @ W2 + b2, softmax over V=32000, 2 recompute
// passes (no logit round-trip). 32 rows/block, 4 cols/thread.
// ---------------------------------------------------------------------------
template <int PASS>
__global__ __launch_bounds__(256, 2)
void head2_kernel(const float* __restrict__ out32,
                  const float* __restrict__ W2,
                  const float* __restrict__ b2,
                  float* __restrict__ partial,   // [B][32]
                  float* __restrict__ out)
{
    __shared__ float A[32][32];      // A[k][r]
    __shared__ float wsum[4][32];
    __shared__ float sinv[32];

    const int tid = threadIdx.x;
    const int vt  = blockIdx.y;          // 0..31
    const int r0  = blockIdx.x * 32;     // row tile base

    for (int i = tid; i < 1024; i += 256) {
        int r = i >> 5, k = i & 31;
        A[k][r] = out32[(r0 + r) * D1_ + k];
    }
    if (PASS == 2 && tid < 32) {
        float s = 0.f;
        #pragma unroll
        for (int v = 0; v < 32; ++v) s += partial[(r0 + tid) * 32 + v];
        sinv[tid] = 1.f / s;
    }
    __syncthreads();

    const int cbeg = vt * 1024;
    float acc[4][32];
    #pragma unroll
    for (int cc = 0; cc < 4; ++cc)
        #pragma unroll
        for (int r = 0; r < 32; ++r) acc[cc][r] = 0.f;

    #pragma unroll 2
    for (int k = 0; k < 32; ++k) {
        float ar[32];
        #pragma unroll
        for (int r = 0; r < 32; ++r) ar[r] = A[k][r];
        #pragma unroll
        for (int cc = 0; cc < 4; ++cc) {
            int cidx = cbeg + tid + cc * 256;
            float w = (cidx < V_) ? W2[k * V_ + cidx] : 0.f;
            #pragma unroll
            for (int r = 0; r < 32; ++r) acc[cc][r] = fmaf(ar[r], w, acc[cc][r]);
        }
    }

    float sumloc[32];
    #pragma unroll
    for (int r = 0; r < 32; ++r) sumloc[r] = 0.f;

    #pragma unroll
    for (int cc = 0; cc < 4; ++cc) {
        int cidx = cbeg + tid + cc * 256;
        if (cidx < V_) {
            float bb = b2[cidx];
            #pragma unroll
            for (int r = 0; r < 32; ++r) {
                float e = __expf(acc[cc][r] + bb);
                if (PASS == 1) sumloc[r] += e;
                else           out[(r0 + r) * V_ + cidx] = e * sinv[r];
            }
        }
    }

    if (PASS == 1) {
        #pragma unroll
        for (int r = 0; r < 32; ++r) {
            float v = sumloc[r];
            #pragma unroll
            for (int off = 32; off; off >>= 1) v += __shfl_xor(v, off, 64);
            if ((tid & 63) == 0) wsum[tid >> 6][r] = v;
        }
        __syncthreads();
        if (tid < 32)
            partial[(r0 + tid) * 32 + vt] =
                wsum[0][tid] + wsum[1][tid] + wsum[2][tid] + wsum[3][tid];
    }
}

// ---------------------------------------------------------------------------
extern "C" void kernel_launch(void* const* d_in, const int* in_sizes, int n_in,
                              void* d_out, int out_size, void* d_ws, size_t ws_size,
                              hipStream_t stream)
{
    (void)in_sizes; (void)n_in; (void)out_size; (void)ws_size;

    const int*   idx = (const int*)  d_in[0];
    const float* emb = (const float*)d_in[1];
    const float* Wx  = (const float*)d_in[2];
    const float* Wh  = (const float*)d_in[3];
    const float* bl  = (const float*)d_in[4];
    const float* W1  = (const float*)d_in[5];
    const float* b1  = (const float*)d_in[6];
    const float* W2  = (const float*)d_in[7];
    const float* b2  = (const float*)d_in[8];
    float* out = (float*)d_out;

    float* h     = (float*)d_ws;               // 4096*64 f32
    float* out32 = h + B_ * H_;                // 4096*32 f32
    float* part  = out32 + B_ * D1_;           // 4096*32 f32

    lstm_mfma_kernel<<<256, 256, 0, stream>>>(idx, emb, Wx, Wh, bl, h);
    head1_kernel<<<(B_ * D1_) / 256, 256, 0, stream>>>(h, W1, b1, out32);

    dim3 g3(B_ / 32, 32);
    head2_kernel<1><<<g3, 256, 0, stream>>>(out32, W2, b2, part, out);
    head2_kernel<2><<<g3, 256, 0, stream>>>(out32, W2, b2, part, out);
}

// Round 4
// 405.164 us; speedup vs baseline: 4.9324x; 1.4783x over previous
//
#include <hip/hip_runtime.h>
#include <hip/hip_bf16.h>

#define B_  4096
#define T_  255
#define V_  32000
#define E_  64
#define H_  64
#define D1_ 32

#define NCT           2000   // V/16 col-tiles
#define NCHUNK        10
#define CT_PER_CHUNK  200    // NCT / NCHUNK
#define CT_PER_WAVE   50     // CT_PER_CHUNK / 4 waves

typedef __attribute__((ext_vector_type(8))) short bf16x8;   // 8 bf16 = 4 VGPR
typedef __attribute__((ext_vector_type(4))) float f32x4;

__device__ __forceinline__ ushort f2bf(float f) {
    __hip_bfloat16 h = __float2bfloat16(f);   // RNE
    return *reinterpret_cast<ushort*>(&h);
}
__device__ __forceinline__ float fast_sigmoid(float x) {
    return __builtin_amdgcn_rcpf(1.f + __expf(-x));
}
__device__ __forceinline__ float fast_tanh(float x) {
    return 1.f - 2.f * __builtin_amdgcn_rcpf(1.f + __expf(2.f * x));
}

// Swizzled byte offset inside a [16 rows][128 bf16] (256 B/row) A-tile.
__device__ __forceinline__ int a_off(int row, int colb) {
    return row * 256 + (colb ^ ((row & 7) << 4));
}

// ---------------------------------------------------------------------------
// Kernel 1: fused embedding-gather + LSTM, bf16 MFMA, gate-split.
// 256 blocks x 512 threads = 8 waves (2/SIMD). Wave (wg = w&3, wh = w>>2)
// computes gates {2wh, 2wh+1} for hidden units [16wg, 16wg+16) = 8 MFMAs.
// Biased z-values exchanged via padded LDS (zex); activation split across
// 128 lanes per unit-group (2 elems/lane, c-state lane-resident).
// A = [x(t) | h(t-1)] bf16 in LDS, double-buffered, XOR-swizzled.
// ---------------------------------------------------------------------------
__global__ __launch_bounds__(512, 2)
void lstm_mfma_kernel(const int* __restrict__ idx,
                      const float* __restrict__ emb,
                      const float* __restrict__ Wx,
                      const float* __restrict__ Wh,
                      const float* __restrict__ b,
                      float* __restrict__ h_out)
{
    __shared__ __align__(16) char abuf[2][4096];     // [buf][16 rows][128 bf16]
    __shared__ float zex[64 * 4 * 17 + 16];          // [j][g][row] pad-17

    const int tid  = threadIdx.x;
    const int lane = tid & 63;
    const int wave = tid >> 6;          // 0..7
    const int wg   = wave & 3;          // unit group
    const int wh   = wave >> 2;         // gate half: 0 -> i,f ; 1 -> g,o
    const int r0   = blockIdx.x * 16;

    const int lrow = lane & 15;
    const int lhi  = lane >> 4;

    // ---- persistent B fragments (2 gates x 4 K-slices) ----
    bf16x8 bw[8];                       // [gg*4 + s]
    const int jcol = wg * 16 + lrow;
    float bias[2];
    #pragma unroll
    for (int gg = 0; gg < 2; ++gg) {
        const int g   = wh * 2 + gg;
        const int col = g * 64 + jcol;
        bias[gg] = b[g * 64 + jcol];
        #pragma unroll
        for (int s = 0; s < 4; ++s) {
            bf16x8 f;
            #pragma unroll
            for (int i = 0; i < 8; ++i) {
                int k = s * 32 + lhi * 8 + i;
                float v = (k < 64) ? Wx[k * 256 + col] : Wh[(k - 64) * 256 + col];
                f[i] = (short)f2bf(v);
            }
            bw[gg * 4 + s] = f;
        }
    }

    // activation assignment: 128 lanes (2 waves of group wg) x 2 elems
    const int arow = lrow;
    const int aj16 = wh * 4 + lhi;          // 0..7
    const int j0   = wg * 16 + aj16;        // unit j (first elem)
    const int j1   = j0 + 8;                // unit j (second elem)

    // x staging: 512 threads, 2 cols each
    const int xrow = tid >> 5;              // 0..15
    const int xcc  = tid & 31;              // 0..31 (col pair)

    // ---- prologue: buf0 = [x(0) | h=0] ----
    {
        *(ushort2*)(&abuf[0][a_off(xrow, 128 + xcc * 4)]) = make_ushort2(0, 0);
        int iv = idx[(r0 + xrow) * T_ + 0];
        float2 xv = *(const float2*)(emb + iv * E_ + xcc * 2);
        *(ushort2*)(&abuf[0][a_off(xrow, xcc * 4)]) =
            make_ushort2(f2bf(xv.x), f2bf(xv.y));
    }
    __syncthreads();

    float cst[2] = {0.f, 0.f};
    float hcur[2] = {0.f, 0.f};

    for (int t = 0; t < T_; ++t) {
        const int p = t & 1;
        const bool havex = (t + 1 < T_);

        // prefetch x(t+1)
        float2 xv;
        if (havex) {
            int iv = idx[(r0 + xrow) * T_ + (t + 1)];
            xv = *(const float2*)(emb + iv * E_ + xcc * 2);
        }

        // z = bias + A @ W  (this wave: 2 gates)
        f32x4 z0 = (f32x4){bias[0], bias[0], bias[0], bias[0]};
        f32x4 z1 = (f32x4){bias[1], bias[1], bias[1], bias[1]};
        #pragma unroll
        for (int s = 0; s < 4; ++s) {
            bf16x8 af = *(const bf16x8*)(&abuf[p][a_off(lrow, s * 64 + lhi * 16)]);
            z0 = __builtin_amdgcn_mfma_f32_16x16x32_bf16(af, bw[s],     z0, 0, 0, 0);
            z1 = __builtin_amdgcn_mfma_f32_16x16x32_bf16(af, bw[4 + s], z1, 0, 0, 0);
        }

        // publish z to zex[j][g][row]
        {
            const int g0 = wh * 2;
            const int base0 = (jcol * 4 + g0) * 17;
            const int base1 = (jcol * 4 + g0 + 1) * 17;
            *(float2*)(&zex[base0 + lhi * 4 + 0]) = make_float2(z0[0], z0[1]);
            *(float2*)(&zex[base0 + lhi * 4 + 2]) = make_float2(z0[2], z0[3]);
            *(float2*)(&zex[base1 + lhi * 4 + 0]) = make_float2(z1[0], z1[1]);
            *(float2*)(&zex[base1 + lhi * 4 + 2]) = make_float2(z1[2], z1[3]);
        }
        __syncthreads();   // zex ready; all A-reads of buf[p] complete

        // activation: 2 elems per lane
        #pragma unroll
        for (int e = 0; e < 2; ++e) {
            const int j = e ? j1 : j0;
            const int zb = j * 68 + arow;   // (j*4+g)*17 + arow, g=0
            float zi = zex[zb];
            float zf = zex[zb + 17];
            float zg = zex[zb + 34];
            float zo = zex[zb + 51];
            float cn = fast_sigmoid(zf) * cst[e] + fast_sigmoid(zi) * fast_tanh(zg);
            cst[e] = cn;
            float hn = fast_sigmoid(zo) * fast_tanh(cn);
            hcur[e] = hn;
            *(ushort*)(&abuf[p ^ 1][a_off(arow, 128 + 2 * j)]) = f2bf(hn);
        }

        // stage x(t+1)
        if (havex)
            *(ushort2*)(&abuf[p ^ 1][a_off(xrow, xcc * 4)]) =
                make_ushort2(f2bf(xv.x), f2bf(xv.y));

        __syncthreads();   // buf[p^1] ready; zex reads complete
    }

    h_out[(r0 + arow) * H_ + j0] = hcur[0];
    h_out[(r0 + arow) * H_ + j1] = hcur[1];
}

// ---------------------------------------------------------------------------
// Kernel 2: out32bf = bf16(relu(h @ W1 + b1))   [4096,64]@[64,32]
// ---------------------------------------------------------------------------
__global__ __launch_bounds__(256)
void head1_kernel(const float* __restrict__ h,
                  const float* __restrict__ W1,
                  const float* __restrict__ b1,
                  ushort* __restrict__ out32bf)
{
    int i = blockIdx.x * 256 + threadIdx.x;   // over 4096*32
    int r = i >> 5, d = i & 31;
    float a = b1[d];
    #pragma unroll
    for (int k = 0; k < 64; ++k)
        a = fmaf(h[r * H_ + k], W1[k * D1_ + d], a);
    out32bf[i] = f2bf(fmaxf(a, 0.f));
}

// ---------------------------------------------------------------------------
// Kernel 2b: repack W2 (fp32 row-major [32][V]) -> bf16 B-frag-linear:
// w2p[ct*512 + l*8 + i] = bf16(W2[(l>>4)*8 + i][ct*16 + (l&15)])
// so lane l of a wave reads its whole B-frag as one 16B load.
// ---------------------------------------------------------------------------
__global__ __launch_bounds__(256)
void repack_w2_kernel(const float* __restrict__ W2, ushort* __restrict__ w2p)
{
    int t = blockIdx.x * 256 + threadIdx.x;   // over NCT*64
    if (t >= NCT * 64) return;
    int ct = t >> 6, l = t & 63;
    int kbase = (l >> 4) * 8, c = ct * 16 + (l & 15);
    ushort tmp[8];
    #pragma unroll
    for (int i = 0; i < 8; ++i)
        tmp[i] = f2bf(W2[(kbase + i) * V_ + c]);
    *(ushort4*)(&w2p[t * 8])     = *(ushort4*)(&tmp[0]);
    *(ushort4*)(&w2p[t * 8 + 4]) = *(ushort4*)(&tmp[4]);
}

// ---------------------------------------------------------------------------
// Kernel 3: logits = out32 @ W2 + b2, softmax over V, via MFMA.
// Each wave: per 16-col tile = 1x 16B A-frag (hoisted), 1x 16B B-load,
// 1 MFMA (K=32 exact), 16 exp. PASS 1 accumulates row-sums; PASS 2 scales.
// Grid (256 rowtiles, 10 chunks); wave covers 50 col-tiles.
// ---------------------------------------------------------------------------
template <int PASS>
__global__ __launch_bounds__(256)
void head2_mfma_kernel(const ushort* __restrict__ out32bf,
                       const ushort* __restrict__ w2p,
                       const float* __restrict__ b2,
                       float* __restrict__ partial,   // [B][NCHUNK]
                       float* __restrict__ out)
{
    __shared__ float red[4][16];
    __shared__ float sinvs[16];

    const int tid  = threadIdx.x;
    const int lane = tid & 63;
    const int w    = tid >> 6;
    const int lrow = lane & 15;
    const int lhi  = lane >> 4;
    const int r0    = blockIdx.x * 16;
    const int chunk = blockIdx.y;

    if (PASS == 2) {
        if (tid < 16) {
            float s = 0.f;
            #pragma unroll
            for (int c = 0; c < NCHUNK; ++c) s += partial[(r0 + tid) * NCHUNK + c];
            sinvs[tid] = 1.f / s;
        }
        __syncthreads();
    }

    // A-frag: lane holds out32[r0+lrow][lhi*8 .. +8]
    const bf16x8 A = *(const bf16x8*)(out32bf + (r0 + lrow) * D1_ + lhi * 8);

    float sacc[4] = {0.f, 0.f, 0.f, 0.f};
    float si[4];
    if (PASS == 2) {
        #pragma unroll
        for (int r = 0; r < 4; ++r) si[r] = sinvs[lhi * 4 + r];
    }

    const int ct0 = chunk * CT_PER_CHUNK + w * CT_PER_WAVE;
    for (int i = 0; i < CT_PER_WAVE; ++i) {
        const int ct = ct0 + i;
        const bf16x8 Bf = *(const bf16x8*)(w2p + ct * 512 + lane * 8);
        f32x4 z = __builtin_amdgcn_mfma_f32_16x16x32_bf16(A, Bf, (f32x4){0.f, 0.f, 0.f, 0.f}, 0, 0, 0);
        const float b2v = b2[ct * 16 + lrow];
        #pragma unroll
        for (int r = 0; r < 4; ++r) {
            float e = __expf(z[r] + b2v);
            if (PASS == 1) sacc[r] += e;
            else out[(size_t)(r0 + lhi * 4 + r) * V_ + ct * 16 + lrow] = e * si[r];
        }
    }

    if (PASS == 1) {
        #pragma unroll
        for (int r = 0; r < 4; ++r) {
            float v = sacc[r];
            #pragma unroll
            for (int off = 1; off < 16; off <<= 1) v += __shfl_xor(v, off, 16);
            if (lrow == 0) red[w][lhi * 4 + r] = v;
        }
        __syncthreads();
        if (tid < 16)
            partial[(r0 + tid) * NCHUNK + chunk] =
                red[0][tid] + red[1][tid] + red[2][tid] + red[3][tid];
    }
}

// ---------------------------------------------------------------------------
extern "C" void kernel_launch(void* const* d_in, const int* in_sizes, int n_in,
                              void* d_out, int out_size, void* d_ws, size_t ws_size,
                              hipStream_t stream)
{
    (void)in_sizes; (void)n_in; (void)out_size; (void)ws_size;

    const int*   idx = (const int*)  d_in[0];
    const float* emb = (const float*)d_in[1];
    const float* Wx  = (const float*)d_in[2];
    const float* Wh  = (const float*)d_in[3];
    const float* bl  = (const float*)d_in[4];
    const float* W1  = (const float*)d_in[5];
    const float* b1  = (const float*)d_in[6];
    const float* W2  = (const float*)d_in[7];
    const float* b2  = (const float*)d_in[8];
    float* out = (float*)d_out;

    float*  ws      = (float*)d_ws;
    float*  h       = ws;                          // 262144 f32
    ushort* out32bf = (ushort*)(ws + 262144);      // 131072 us (65536 f)
    ushort* w2p     = (ushort*)(ws + 262144 + 65536);   // 1024000 us (512000 f)
    float*  part    = ws + 262144 + 65536 + 512000;     // 40960 f32

    repack_w2_kernel<<<(NCT * 64 + 255) / 256, 256, 0, stream>>>(W2, w2p);
    lstm_mfma_kernel<<<256, 512, 0, stream>>>(idx, emb, Wx, Wh, bl, h);
    head1_kernel<<<(B_ * D1_) / 256, 256, 0, stream>>>(h, W1, b1, out32bf);

    dim3 g3(B_ / 16, NCHUNK);
    head2_mfma_kernel<1><<<g3, 256, 0, stream>>>(out32bf, w2p, b2, part, out);
    head2_mfma_kernel<2><<<g3, 256, 0, stream>>>(out32bf, w2p, b2, part, out);
}

// Round 5
// 396.705 us; speedup vs baseline: 5.0376x; 1.0213x over previous
//
#include <hip/hip_runtime.h>
#include <hip/hip_bf16.h>

#define B_  4096
#define T_  255
#define V_  32000
#define E_  64
#define H_  64
#define D1_ 32

#define NCT           2000   // V/16 col-tiles
#define NCHUNK        10
#define CT_PER_CHUNK  200    // NCT / NCHUNK
#define CT_PER_WAVE   50     // CT_PER_CHUNK / 4 waves

#define ZG 1152              // 64 * 18 (row-stride-18 padded gate plane)

typedef __attribute__((ext_vector_type(8))) short bf16x8;   // 8 bf16 = 4 VGPR
typedef __attribute__((ext_vector_type(4))) float f32x4;

__device__ __forceinline__ ushort f2bf(float f) {
    __hip_bfloat16 h = __float2bfloat16(f);   // RNE
    return *reinterpret_cast<ushort*>(&h);
}
__device__ __forceinline__ float fast_sigmoid(float x) {
    return __builtin_amdgcn_rcpf(1.f + __expf(-x));
}
__device__ __forceinline__ float fast_tanh(float x) {
    return 1.f - 2.f * __builtin_amdgcn_rcpf(1.f + __expf(2.f * x));
}

// Swizzled byte offset inside a [16 rows][128 bf16] (256 B/row) A-tile.
__device__ __forceinline__ int a_off(int row, int colb) {
    return row * 256 + (colb ^ ((row & 7) << 4));
}

// ---------------------------------------------------------------------------
// Kernel 1: fused embedding-gather + LSTM, bf16 MFMA, gate-split, deep
// emb prefetch. 256 blocks x 512 threads = 8 waves (2/SIMD).
// Wave (wg=w&3, wh=w>>2) computes gates {2wh,2wh+1} for units [16wg,16wg+16).
// idx block-slice staged once in LDS; emb gathered 3 steps ahead via a
// 2-register pipeline (load->use distance = 2 steps, covers HBM latency).
// z exchanged via zex[g][j][row] stride-18 (<=2-way bank conflicts).
// ---------------------------------------------------------------------------
__global__ __launch_bounds__(512, 2)
void lstm_mfma_kernel(const int* __restrict__ idx,
                      const float* __restrict__ emb,
                      const float* __restrict__ Wx,
                      const float* __restrict__ Wh,
                      const float* __restrict__ b,
                      float* __restrict__ h_out)
{
    __shared__ __align__(16) char abuf[2][4096];   // [buf][16 rows][128 bf16]
    __shared__ float zex[4 * ZG];                  // [g][j][row], stride 18
    __shared__ int   idxs[16 * 256];               // [row][t]

    const int tid  = threadIdx.x;
    const int lane = tid & 63;
    const int wave = tid >> 6;          // 0..7
    const int wg   = wave & 3;          // unit group
    const int wh   = wave >> 2;         // gate half: 0 -> i,f ; 1 -> g,o
    const int r0   = blockIdx.x * 16;

    const int lrow = lane & 15;
    const int lhi  = lane >> 4;

    // ---- persistent B fragments (2 gates x 4 K-slices) ----
    bf16x8 bw[8];                       // [gg*4 + s]
    const int jcol = wg * 16 + lrow;
    float bias[2];
    #pragma unroll
    for (int gg = 0; gg < 2; ++gg) {
        const int g   = wh * 2 + gg;
        const int col = g * 64 + jcol;
        bias[gg] = b[g * 64 + jcol];
        #pragma unroll
        for (int s = 0; s < 4; ++s) {
            bf16x8 f;
            #pragma unroll
            for (int i = 0; i < 8; ++i) {
                int k = s * 32 + lhi * 8 + i;
                float v = (k < 64) ? Wx[k * 256 + col] : Wh[(k - 64) * 256 + col];
                f[i] = (short)f2bf(v);
            }
            bw[gg * 4 + s] = f;
        }
    }

    // activation assignment
    const int arow = lrow;
    const int j0   = wg * 16 + wh * 4 + lhi;   // first unit
    const int j1   = j0 + 8;                   // second unit

    // x staging: 512 threads -> (row, col pair)
    const int xrow = tid >> 5;              // 0..15
    const int xcc  = tid & 31;              // 0..31

    // ---- stage idx slice into LDS (coalesced) ----
    {
        const int row = tid >> 5, c0 = tid & 31;
        #pragma unroll
        for (int k = 0; k < 8; ++k) {
            int t = c0 + 32 * k;
            if (t < T_) idxs[row * 256 + t] = idx[(r0 + row) * T_ + t];
        }
    }

    // ---- prologue: stage x(0); preload x(1), x(2) into regs ----
    float2 xcur, xva;
    {
        *(ushort2*)(&abuf[0][a_off(xrow, 128 + xcc * 4)]) = make_ushort2(0, 0);
        int iv0 = idx[(r0 + xrow) * T_ + 0];
        float2 x0 = *(const float2*)(emb + iv0 * E_ + xcc * 2);
        *(ushort2*)(&abuf[0][a_off(xrow, xcc * 4)]) =
            make_ushort2(f2bf(x0.x), f2bf(x0.y));
        int iv1 = idx[(r0 + xrow) * T_ + 1];
        xcur = *(const float2*)(emb + iv1 * E_ + xcc * 2);
        int iv2 = idx[(r0 + xrow) * T_ + 2];
        xva  = *(const float2*)(emb + iv2 * E_ + xcc * 2);
    }
    __syncthreads();   // abuf[0], idxs ready

    float cst[2]  = {0.f, 0.f};
    float hcur[2] = {0.f, 0.f};

    for (int t = 0; t < T_; ++t) {
        const int p = t & 1;

        // issue emb gather for t+3 (idx from LDS; consumed 2 steps later)
        float2 xnew;
        const int tload = t + 3;
        const bool haveload = (tload < T_);
        if (haveload) {
            int iv = idxs[xrow * 256 + tload];
            xnew = *(const float2*)(emb + iv * E_ + xcc * 2);
        }

        // z = bias + A @ W  (this wave: 2 gates)
        f32x4 z0 = (f32x4){bias[0], bias[0], bias[0], bias[0]};
        f32x4 z1 = (f32x4){bias[1], bias[1], bias[1], bias[1]};
        #pragma unroll
        for (int s = 0; s < 4; ++s) {
            bf16x8 af = *(const bf16x8*)(&abuf[p][a_off(lrow, s * 64 + lhi * 16)]);
            z0 = __builtin_amdgcn_mfma_f32_16x16x32_bf16(af, bw[s],     z0, 0, 0, 0);
            z1 = __builtin_amdgcn_mfma_f32_16x16x32_bf16(af, bw[4 + s], z1, 0, 0, 0);
        }

        // publish z: zex[g][jcol][rows lhi*4..+3], two b64 writes per gate
        {
            const int g0 = wh * 2;
            float* p0 = &zex[g0 * ZG + jcol * 18 + lhi * 4];
            *(float2*)(p0)     = make_float2(z0[0], z0[1]);
            *(float2*)(p0 + 2) = make_float2(z0[2], z0[3]);
            float* p1 = p0 + ZG;
            *(float2*)(p1)     = make_float2(z1[0], z1[1]);
            *(float2*)(p1 + 2) = make_float2(z1[2], z1[3]);
        }
        __syncthreads();   // zex ready; all A-reads of buf[p] complete

        // activation: 2 elems per lane
        #pragma unroll
        for (int e = 0; e < 2; ++e) {
            const int j = e ? j1 : j0;
            const int zb = j * 18 + arow;
            float zi = zex[zb];
            float zf = zex[zb + ZG];
            float zg = zex[zb + 2 * ZG];
            float zo = zex[zb + 3 * ZG];
            float cn = fast_sigmoid(zf) * cst[e] + fast_sigmoid(zi) * fast_tanh(zg);
            cst[e] = cn;
            float hn = fast_sigmoid(zo) * fast_tanh(cn);
            hcur[e] = hn;
            *(ushort*)(&abuf[p ^ 1][a_off(arow, 128 + 2 * j)]) = f2bf(hn);
        }

        // stage x(t+1) from the pipeline register
        if (t + 1 < T_)
            *(ushort2*)(&abuf[p ^ 1][a_off(xrow, xcc * 4)]) =
                make_ushort2(f2bf(xcur.x), f2bf(xcur.y));

        __syncthreads();   // buf[p^1] ready; zex reads complete

        xcur = xva;
        if (haveload) xva = xnew;
    }

    h_out[(r0 + arow) * H_ + j0] = hcur[0];
    h_out[(r0 + arow) * H_ + j1] = hcur[1];
}

// ---------------------------------------------------------------------------
// Kernel 2: out32bf = bf16(relu(h @ W1 + b1))   [4096,64]@[64,32]
// ---------------------------------------------------------------------------
__global__ __launch_bounds__(256)
void head1_kernel(const float* __restrict__ h,
                  const float* __restrict__ W1,
                  const float* __restrict__ b1,
                  ushort* __restrict__ out32bf)
{
    int i = blockIdx.x * 256 + threadIdx.x;   // over 4096*32
    int r = i >> 5, d = i & 31;
    float a = b1[d];
    #pragma unroll
    for (int k = 0; k < 64; ++k)
        a = fmaf(h[r * H_ + k], W1[k * D1_ + d], a);
    out32bf[i] = f2bf(fmaxf(a, 0.f));
}

// ---------------------------------------------------------------------------
// Kernel 2b: repack W2 (fp32 row-major [32][V]) -> bf16 B-frag-linear.
// ---------------------------------------------------------------------------
__global__ __launch_bounds__(256)
void repack_w2_kernel(const float* __restrict__ W2, ushort* __restrict__ w2p)
{
    int t = blockIdx.x * 256 + threadIdx.x;   // over NCT*64
    if (t >= NCT * 64) return;
    int ct = t >> 6, l = t & 63;
    int kbase = (l >> 4) * 8, c = ct * 16 + (l & 15);
    ushort tmp[8];
    #pragma unroll
    for (int i = 0; i < 8; ++i)
        tmp[i] = f2bf(W2[(kbase + i) * V_ + c]);
    *(ushort4*)(&w2p[t * 8])     = *(ushort4*)(&tmp[0]);
    *(ushort4*)(&w2p[t * 8 + 4]) = *(ushort4*)(&tmp[4]);
}

// ---------------------------------------------------------------------------
// Kernel 3: logits = out32 @ W2 + b2, softmax over V, via MFMA.
// PASS 1: per-chunk row sums of exp; PASS 2: scaled write.
// ---------------------------------------------------------------------------
template <int PASS>
__global__ __launch_bounds__(256)
void head2_mfma_kernel(const ushort* __restrict__ out32bf,
                       const ushort* __restrict__ w2p,
                       const float* __restrict__ b2,
                       float* __restrict__ partial,   // [B][NCHUNK]
                       float* __restrict__ out)
{
    __shared__ float red[4][16];
    __shared__ float sinvs[16];

    const int tid  = threadIdx.x;
    const int lane = tid & 63;
    const int w    = tid >> 6;
    const int lrow = lane & 15;
    const int lhi  = lane >> 4;
    const int r0    = blockIdx.x * 16;
    const int chunk = blockIdx.y;

    if (PASS == 2) {
        if (tid < 16) {
            float s = 0.f;
            #pragma unroll
            for (int c = 0; c < NCHUNK; ++c) s += partial[(r0 + tid) * NCHUNK + c];
            sinvs[tid] = 1.f / s;
        }
        __syncthreads();
    }

    const bf16x8 A = *(const bf16x8*)(out32bf + (r0 + lrow) * D1_ + lhi * 8);

    float sacc[4] = {0.f, 0.f, 0.f, 0.f};
    float si[4];
    if (PASS == 2) {
        #pragma unroll
        for (int r = 0; r < 4; ++r) si[r] = sinvs[lhi * 4 + r];
    }

    const int ct0 = chunk * CT_PER_CHUNK + w * CT_PER_WAVE;
    for (int i = 0; i < CT_PER_WAVE; ++i) {
        const int ct = ct0 + i;
        const bf16x8 Bf = *(const bf16x8*)(w2p + ct * 512 + lane * 8);
        f32x4 z = __builtin_amdgcn_mfma_f32_16x16x32_bf16(A, Bf, (f32x4){0.f, 0.f, 0.f, 0.f}, 0, 0, 0);
        const float b2v = b2[ct * 16 + lrow];
        #pragma unroll
        for (int r = 0; r < 4; ++r) {
            float e = __expf(z[r] + b2v);
            if (PASS == 1) sacc[r] += e;
            else out[(size_t)(r0 + lhi * 4 + r) * V_ + ct * 16 + lrow] = e * si[r];
        }
    }

    if (PASS == 1) {
        #pragma unroll
        for (int r = 0; r < 4; ++r) {
            float v = sacc[r];
            #pragma unroll
            for (int off = 1; off < 16; off <<= 1) v += __shfl_xor(v, off, 16);
            if (lrow == 0) red[w][lhi * 4 + r] = v;
        }
        __syncthreads();
        if (tid < 16)
            partial[(r0 + tid) * NCHUNK + chunk] =
                red[0][tid] + red[1][tid] + red[2][tid] + red[3][tid];
    }
}

// ---------------------------------------------------------------------------
extern "C" void kernel_launch(void* const* d_in, const int* in_sizes, int n_in,
                              void* d_out, int out_size, void* d_ws, size_t ws_size,
                              hipStream_t stream)
{
    (void)in_sizes; (void)n_in; (void)out_size; (void)ws_size;

    const int*   idx = (const int*)  d_in[0];
    const float* emb = (const float*)d_in[1];
    const float* Wx  = (const float*)d_in[2];
    const float* Wh  = (const float*)d_in[3];
    const float* bl  = (const float*)d_in[4];
    const float* W1  = (const float*)d_in[5];
    const float* b1  = (const float*)d_in[6];
    const float* W2  = (const float*)d_in[7];
    const float* b2  = (const float*)d_in[8];
    float* out = (float*)d_out;

    float*  ws      = (float*)d_ws;
    float*  h       = ws;                          // 262144 f32
    ushort* out32bf = (ushort*)(ws + 262144);      // 131072 us
    ushort* w2p     = (ushort*)(ws + 262144 + 65536);   // 1024000 us
    float*  part    = ws + 262144 + 65536 + 512000;     // 40960 f32

    repack_w2_kernel<<<(NCT * 64 + 255) / 256, 256, 0, stream>>>(W2, w2p);
    lstm_mfma_kernel<<<256, 512, 0, stream>>>(idx, emb, Wx, Wh, bl, h);
    head1_kernel<<<(B_ * D1_) / 256, 256, 0, stream>>>(h, W1, b1, out32bf);

    dim3 g3(B_ / 16, NCHUNK);
    head2_mfma_kernel<1><<<g3, 256, 0, stream>>>(out32bf, w2p, b2, part, out);
    head2_mfma_kernel<2><<<g3, 256, 0, stream>>>(out32bf, w2p, b2, part, out);
}

// Round 6
// 374.383 us; speedup vs baseline: 5.3380x; 1.0596x over previous
//
#include <hip/hip_runtime.h>
#include <hip/hip_bf16.h>

#define B_  4096
#define T_  255
#define V_  32000
#define E_  64
#define H_  64
#define D1_ 32

#define NCT           2000   // V/16 col-tiles
#define NCHUNK        10
#define CT_PER_CHUNK  200    // NCT / NCHUNK
#define CT_PER_WAVE   50     // CT_PER_CHUNK / 4 waves

typedef __attribute__((ext_vector_type(8))) short bf16x8;   // 8 bf16 = 4 VGPR
typedef __attribute__((ext_vector_type(4))) float f32x4;

__device__ __forceinline__ ushort f2bf(float f) {
    __hip_bfloat16 h = __float2bfloat16(f);   // RNE
    return *reinterpret_cast<ushort*>(&h);
}
__device__ __forceinline__ float fast_sigmoid(float x) {
    return __builtin_amdgcn_rcpf(1.f + __expf(-x));
}
__device__ __forceinline__ float fast_tanh(float x) {
    return 1.f - 2.f * __builtin_amdgcn_rcpf(1.f + __expf(2.f * x));
}

// Swizzled byte offset in a [16 rows][64 bf16] (128 B/row) h-tile.
// XOR row bits into the 16B-slot bits: A-frag reads (16 rows, same slot)
// would otherwise be a 16-way bank conflict; swizzled -> 2-way (free).
__device__ __forceinline__ int hswz(int row, int colb) {
    return row * 128 + (colb ^ ((row & 7) << 4));
}

// ---------------------------------------------------------------------------
// Kernel 0: one-time emb fp32 -> bf16 (gatherable as A-fragments).
// ---------------------------------------------------------------------------
__global__ __launch_bounds__(256)
void emb2bf_kernel(const float* __restrict__ emb, ushort* __restrict__ emb_bf)
{
    int i = blockIdx.x * 256 + threadIdx.x;      // over V*64/8 = 256000
    const float4 a = ((const float4*)emb)[i * 2];
    const float4 b = ((const float4*)emb)[i * 2 + 1];
    ushort t[8] = { f2bf(a.x), f2bf(a.y), f2bf(a.z), f2bf(a.w),
                    f2bf(b.x), f2bf(b.y), f2bf(b.z), f2bf(b.w) };
    *(ushort4*)(&emb_bf[i * 8])     = *(ushort4*)(&t[0]);
    *(ushort4*)(&emb_bf[i * 8 + 4]) = *(ushort4*)(&t[4]);
}

// ---------------------------------------------------------------------------
// Kernel 1: fused embedding-gather + LSTM, bf16 MFMA.
// 256 blocks x 256 threads (4 waves, 1/SIMD). Wave w computes ALL 4 gates
// for hidden units [16w,16w+16) over the block's 16 batch rows -> activation
// is wave-local (C-frag: lane owns unit j=w*16+lrow, rows lhi*4..+3).
// Cross-wave data = h only (2KB double-buffered LDS, XOR-swizzled).
// x comes straight from global (pre-bf16 emb) into A-frag VGPRs, gathered
// 2 steps ahead. ONE raw barrier per step (lgkmcnt only, NO vmcnt drain),
// so x gathers stay in flight across barriers.
// ---------------------------------------------------------------------------
__global__ __launch_bounds__(256)
void lstm_mfma_kernel(const int* __restrict__ idx,
                      const ushort* __restrict__ emb_bf,
                      const float* __restrict__ Wx,
                      const float* __restrict__ Wh,
                      const float* __restrict__ b,
                      float* __restrict__ h_out)
{
    __shared__ __align__(16) char hbuf[2][2048];   // [buf][16 rows][64 bf16]
    __shared__ int idxs[16 * 257];                 // [row][t], stride 257

    const int tid  = threadIdx.x;
    const int lane = tid & 63;
    const int w    = tid >> 6;          // 0..3: unit group
    const int r0   = blockIdx.x * 16;

    const int lrow = lane & 15;
    const int lhi  = lane >> 4;
    const int jcol = w * 16 + lrow;     // this lane's hidden unit

    // ---- persistent B fragments: 4 gates x 4 K-slices = 64 VGPR ----
    bf16x8 bw[16];
    float bias[4];
    #pragma unroll
    for (int g = 0; g < 4; ++g) {
        const int col = g * 64 + jcol;
        bias[g] = b[col];
        #pragma unroll
        for (int s = 0; s < 4; ++s) {
            bf16x8 f;
            #pragma unroll
            for (int i = 0; i < 8; ++i) {
                int k = s * 32 + lhi * 8 + i;
                float v = (k < 64) ? Wx[k * 256 + col] : Wh[(k - 64) * 256 + col];
                f[i] = (short)f2bf(v);
            }
            bw[g * 4 + s] = f;
        }
    }

    // ---- stage idx slice (coalesced), zero h-buffer 0 ----
    {
        const int row = tid >> 4, tc = tid & 15;
        #pragma unroll
        for (int k = 0; k < 16; ++k) {
            int t = k * 16 + tc;
            if (t < T_) idxs[row * 257 + t] = idx[(r0 + row) * T_ + t];
        }
        ((float2*)hbuf[0])[tid] = make_float2(0.f, 0.f);
    }
    __syncthreads();

    // ---- x-fragment pipeline (2 steps deep), straight from global ----
    bf16x8 xc0, xc1, xn0, xn1;
    {
        int iv = idxs[lrow * 257 + 0];
        xc0 = *(const bf16x8*)(emb_bf + iv * 64 + lhi * 8);
        xc1 = *(const bf16x8*)(emb_bf + iv * 64 + 32 + lhi * 8);
        iv = idxs[lrow * 257 + 1];
        xn0 = *(const bf16x8*)(emb_bf + iv * 64 + lhi * 8);
        xn1 = *(const bf16x8*)(emb_bf + iv * 64 + 32 + lhi * 8);
    }

    float cst[4]  = {0.f, 0.f, 0.f, 0.f};
    float hreg[4] = {0.f, 0.f, 0.f, 0.f};

    for (int t = 0; t < T_; ++t) {
        const int p = t & 1;

        // h A-frags (K-slices 2,3) from swizzled LDS
        bf16x8 ah2 = *(const bf16x8*)(&hbuf[p][hswz(lrow, lhi * 16)]);
        bf16x8 ah3 = *(const bf16x8*)(&hbuf[p][hswz(lrow, 64 + lhi * 16)]);

        // z[g] = bias + [x|h] @ W(:,gate g)  — 4 independent chains of 4
        f32x4 z[4];
        #pragma unroll
        for (int g = 0; g < 4; ++g) z[g] = (f32x4){bias[g], bias[g], bias[g], bias[g]};
        #pragma unroll
        for (int g = 0; g < 4; ++g) z[g] = __builtin_amdgcn_mfma_f32_16x16x32_bf16(xc0, bw[g * 4 + 0], z[g], 0, 0, 0);
        #pragma unroll
        for (int g = 0; g < 4; ++g) z[g] = __builtin_amdgcn_mfma_f32_16x16x32_bf16(xc1, bw[g * 4 + 1], z[g], 0, 0, 0);
        #pragma unroll
        for (int g = 0; g < 4; ++g) z[g] = __builtin_amdgcn_mfma_f32_16x16x32_bf16(ah2, bw[g * 4 + 2], z[g], 0, 0, 0);
        #pragma unroll
        for (int g = 0; g < 4; ++g) z[g] = __builtin_amdgcn_mfma_f32_16x16x32_bf16(ah3, bw[g * 4 + 3], z[g], 0, 0, 0);

        // rotate x pipeline; issue gathers for t+2 (stay in flight across
        // the raw barrier — no vmcnt(0) drain)
        xc0 = xn0; xc1 = xn1;
        if (t + 2 < T_) {
            int iv = idxs[lrow * 257 + (t + 2)];
            xn0 = *(const bf16x8*)(emb_bf + iv * 64 + lhi * 8);
            xn1 = *(const bf16x8*)(emb_bf + iv * 64 + 32 + lhi * 8);
        }

        // activation (wave-local): lane owns unit jcol, batch rows lhi*4+r
        #pragma unroll
        for (int r = 0; r < 4; ++r) {
            float cn = fast_sigmoid(z[1][r]) * cst[r]
                     + fast_sigmoid(z[0][r]) * fast_tanh(z[2][r]);
            cst[r] = cn;
            float hn = fast_sigmoid(z[3][r]) * fast_tanh(cn);
            hreg[r] = hn;
            const int row = lhi * 4 + r;
            *(ushort*)(&hbuf[p ^ 1][hswz(row, 2 * jcol)]) = f2bf(hn);
        }

        // LDS-only fence + raw barrier: h(t) visible to all waves; global
        // x-prefetch NOT drained.
        asm volatile("s_waitcnt lgkmcnt(0)\n\ts_barrier" ::: "memory");
    }

    #pragma unroll
    for (int r = 0; r < 4; ++r)
        h_out[(r0 + lhi * 4 + r) * H_ + jcol] = hreg[r];
}

// ---------------------------------------------------------------------------
// Kernel 2: out32bf = bf16(relu(h @ W1 + b1))   [4096,64]@[64,32]
// ---------------------------------------------------------------------------
__global__ __launch_bounds__(256)
void head1_kernel(const float* __restrict__ h,
                  const float* __restrict__ W1,
                  const float* __restrict__ b1,
                  ushort* __restrict__ out32bf)
{
    int i = blockIdx.x * 256 + threadIdx.x;   // over 4096*32
    int r = i >> 5, d = i & 31;
    float a = b1[d];
    #pragma unroll
    for (int k = 0; k < 64; ++k)
        a = fmaf(h[r * H_ + k], W1[k * D1_ + d], a);
    out32bf[i] = f2bf(fmaxf(a, 0.f));
}

// ---------------------------------------------------------------------------
// Kernel 2b: repack W2 (fp32 row-major [32][V]) -> bf16 B-frag-linear.
// ---------------------------------------------------------------------------
__global__ __launch_bounds__(256)
void repack_w2_kernel(const float* __restrict__ W2, ushort* __restrict__ w2p)
{
    int t = blockIdx.x * 256 + threadIdx.x;   // over NCT*64
    if (t >= NCT * 64) return;
    int ct = t >> 6, l = t & 63;
    int kbase = (l >> 4) * 8, c = ct * 16 + (l & 15);
    ushort tmp[8];
    #pragma unroll
    for (int i = 0; i < 8; ++i)
        tmp[i] = f2bf(W2[(kbase + i) * V_ + c]);
    *(ushort4*)(&w2p[t * 8])     = *(ushort4*)(&tmp[0]);
    *(ushort4*)(&w2p[t * 8 + 4]) = *(ushort4*)(&tmp[4]);
}

// ---------------------------------------------------------------------------
// Kernel 3: logits = out32 @ W2 + b2, softmax over V, via MFMA.
// PASS 1: per-chunk row sums of exp; PASS 2: scaled write.
// ---------------------------------------------------------------------------
template <int PASS>
__global__ __launch_bounds__(256)
void head2_mfma_kernel(const ushort* __restrict__ out32bf,
                       const ushort* __restrict__ w2p,
                       const float* __restrict__ b2,
                       float* __restrict__ partial,   // [B][NCHUNK]
                       float* __restrict__ out)
{
    __shared__ float red[4][16];
    __shared__ float sinvs[16];

    const int tid  = threadIdx.x;
    const int lane = tid & 63;
    const int w    = tid >> 6;
    const int lrow = lane & 15;
    const int lhi  = lane >> 4;
    const int r0    = blockIdx.x * 16;
    const int chunk = blockIdx.y;

    if (PASS == 2) {
        if (tid < 16) {
            float s = 0.f;
            #pragma unroll
            for (int c = 0; c < NCHUNK; ++c) s += partial[(r0 + tid) * NCHUNK + c];
            sinvs[tid] = 1.f / s;
        }
        __syncthreads();
    }

    const bf16x8 A = *(const bf16x8*)(out32bf + (r0 + lrow) * D1_ + lhi * 8);

    float sacc[4] = {0.f, 0.f, 0.f, 0.f};
    float si[4];
    if (PASS == 2) {
        #pragma unroll
        for (int r = 0; r < 4; ++r) si[r] = sinvs[lhi * 4 + r];
    }

    const int ct0 = chunk * CT_PER_CHUNK + w * CT_PER_WAVE;
    for (int i = 0; i < CT_PER_WAVE; ++i) {
        const int ct = ct0 + i;
        const bf16x8 Bf = *(const bf16x8*)(w2p + ct * 512 + lane * 8);
        f32x4 z = __builtin_amdgcn_mfma_f32_16x16x32_bf16(A, Bf, (f32x4){0.f, 0.f, 0.f, 0.f}, 0, 0, 0);
        const float b2v = b2[ct * 16 + lrow];
        #pragma unroll
        for (int r = 0; r < 4; ++r) {
            float e = __expf(z[r] + b2v);
            if (PASS == 1) sacc[r] += e;
            else out[(size_t)(r0 + lhi * 4 + r) * V_ + ct * 16 + lrow] = e * si[r];
        }
    }

    if (PASS == 1) {
        #pragma unroll
        for (int r = 0; r < 4; ++r) {
            float v = sacc[r];
            #pragma unroll
            for (int off = 1; off < 16; off <<= 1) v += __shfl_xor(v, off, 16);
            if (lrow == 0) red[w][lhi * 4 + r] = v;
        }
        __syncthreads();
        if (tid < 16)
            partial[(r0 + tid) * NCHUNK + chunk] =
                red[0][tid] + red[1][tid] + red[2][tid] + red[3][tid];
    }
}

// ---------------------------------------------------------------------------
extern "C" void kernel_launch(void* const* d_in, const int* in_sizes, int n_in,
                              void* d_out, int out_size, void* d_ws, size_t ws_size,
                              hipStream_t stream)
{
    (void)in_sizes; (void)n_in; (void)out_size; (void)ws_size;

    const int*   idx = (const int*)  d_in[0];
    const float* emb = (const float*)d_in[1];
    const float* Wx  = (const float*)d_in[2];
    const float* Wh  = (const float*)d_in[3];
    const float* bl  = (const float*)d_in[4];
    const float* W1  = (const float*)d_in[5];
    const float* b1  = (const float*)d_in[6];
    const float* W2  = (const float*)d_in[7];
    const float* b2  = (const float*)d_in[8];
    float* out = (float*)d_out;

    float*  ws      = (float*)d_ws;
    float*  h       = ws;                                    // 262144 f32
    ushort* out32bf = (ushort*)(ws + 262144);                // 131072 us
    ushort* w2p     = (ushort*)(ws + 262144 + 65536);        // 1024000 us
    float*  part    = ws + 262144 + 65536 + 512000;          // 40960 f32
    ushort* emb_bf  = (ushort*)(ws + 262144 + 65536 + 512000 + 40960);  // 2048000 us

    emb2bf_kernel<<<(V_ * E_ / 8) / 256, 256, 0, stream>>>(emb, emb_bf);
    repack_w2_kernel<<<(NCT * 64 + 255) / 256, 256, 0, stream>>>(W2, w2p);
    lstm_mfma_kernel<<<256, 256, 0, stream>>>(idx, emb_bf, Wx, Wh, bl, h);
    head1_kernel<<<(B_ * D1_) / 256, 256, 0, stream>>>(h, W1, b1, out32bf);

    dim3 g3(B_ / 16, NCHUNK);
    head2_mfma_kernel<1><<<g3, 256, 0, stream>>>(out32bf, w2p, b2, part, out);
    head2_mfma_kernel<2><<<g3, 256, 0, stream>>>(out32bf, w2p, b2, part, out);
}